// Round 10
// baseline (368.712 us; speedup 1.0000x reference)
//
#include <hip/hip_runtime.h>
#include <stdint.h>

#define DIMC 1536
#define LTOK 3072
#define HEADS 12
#define HD 128
#define FS 384            // H*W = 16*24
#define MAXATTN 1920
#define HTOK 1152         // first heavy token (qf>=3, 4-way K-split)
#define NHT 1920          // heavy tokens
#define MTOK 384          // first mid token (qf 1..2, 2-way split)
#define NMT 768           // mid tokens

typedef __attribute__((ext_vector_type(4))) float f32x4;
typedef __attribute__((ext_vector_type(8))) short bf16x8;
typedef __attribute__((ext_vector_type(4))) unsigned int u32x4;

__device__ __forceinline__ unsigned short f2bf(float f) {
  union { float f; unsigned int u; } c; c.f = f;
  unsigned int u = c.u + 0x7fffu + ((c.u >> 16) & 1u);   // RNE
  return (unsigned short)(u >> 16);
}
__device__ __forceinline__ float bf2f(unsigned short s) {
  union { unsigned int u; float f; } c; c.u = (unsigned int)s << 16; return c.f;
}

// async global->LDS DMA, 16B per lane; LDS dest must be wave-uniform base +
// lane*16 (all our staging offsets are tid*16B -> satisfied).
__device__ __forceinline__ void dma16(const void* g, void* l) {
  __builtin_amdgcn_global_load_lds(
      (const __attribute__((address_space(1))) unsigned int*)g,
      (__attribute__((address_space(3))) unsigned int*)l, 16, 0, 0);
}

// key permutation inside each 64-key tile: group G -> g3*8+g1*4+g0*2+g2,
// chosen so the attention PV B-fragment IS the softmax output registers.
__device__ __forceinline__ int vperm4(int G) {
  return (((G >> 3) & 1) << 3) | (((G >> 1) & 1) << 2) | ((G & 1) << 1) | ((G >> 2) & 1);
}

// ---------------- fused fp32 -> bf16 conversion for all 5 tensors ----------------
__global__ __launch_bounds__(256)
void cvt_all_k(const float* __restrict__ x, const float* __restrict__ wq,
               const float* __restrict__ wk, const float* __restrict__ wv,
               const float* __restrict__ wo,
               unsigned short* __restrict__ xb, unsigned short* __restrict__ wqb,
               unsigned short* __restrict__ wkb, unsigned short* __restrict__ wvb,
               unsigned short* __restrict__ wob)
{
  const int i = blockIdx.x * 256 + threadIdx.x;      // uint4 index
  const int n0 = LTOK * DIMC / 4;
  const int nw = DIMC * DIMC / 4;
  const float* src; unsigned short* dst; int off;
  if (i < n0) { src = x; dst = xb; off = i; }
  else {
    int j = i - n0; int w = j / nw; off = j - w * nw;
    src = (w == 0) ? wq : (w == 1) ? wk : (w == 2) ? wv : wo;
    dst = (w == 0) ? wqb : (w == 1) ? wkb : (w == 2) ? wvb : wob;
  }
  float4 f = ((const float4*)src)[off];
  uint2 o;
  o.x = (unsigned int)f2bf(f.x) | ((unsigned int)f2bf(f.y) << 16);
  o.y = (unsigned int)f2bf(f.z) | ((unsigned int)f2bf(f.w) << 16);
  ((uint2*)dst)[off] = o;
}

// ---------------- QKV GEMM: 128x128 tile, BK=64, 256 thr, single-buffer -------
// XOR chunk swizzle on the GLOBAL source column during staging; read side
// applies the same XOR. z==2 writes V transposed + vperm4-permuted into vt.
__global__ __launch_bounds__(256)
void gemm_qkv(const unsigned short* __restrict__ A,
              const unsigned short* __restrict__ B0,
              const unsigned short* __restrict__ B1,
              const unsigned short* __restrict__ B2,
              const float* __restrict__ bias0,
              const float* __restrict__ bias1,
              const float* __restrict__ bias2,
              unsigned short* __restrict__ o0, unsigned short* __restrict__ o1,
              unsigned short* __restrict__ vt)
{
  const int z = blockIdx.z;
  const unsigned short* Bw = (z == 0) ? B0 : (z == 1) ? B1 : B2;
  const float* bias = (z == 0) ? bias0 : (z == 1) ? bias1 : bias2;

  __shared__ __align__(16) unsigned short lA[128 * 64];
  __shared__ __align__(16) unsigned short lB[128 * 64];

  const int tid = threadIdx.x;
  const int wave = tid >> 6;
  const int lane = tid & 63;
  const int m0 = blockIdx.y * 128;
  const int n0 = blockIdx.x * 128;
  const int wm = (wave >> 1) * 64;
  const int wn = (wave & 1) * 64;

  f32x4 acc[4][4] = {};

  const int srow = tid >> 3;                    // 0..31
  const int scol = ((tid & 7) ^ (srow & 7)) * 8;
  const unsigned short* ga = A  + (size_t)(m0 + srow) * DIMC + scol;
  const unsigned short* gb = Bw + (size_t)(n0 + srow) * DIMC + scol;
  unsigned short* la = lA + tid * 8;
  unsigned short* lb = lB + tid * 8;

  const int fr = lane & 15;
  const int g = lane >> 4;
  const int fx = fr & 7;

  for (int k0 = 0; k0 < DIMC; k0 += 64) {
    dma16(ga + k0,                     la);
    dma16(ga + k0 + (size_t)32 * DIMC, la + 2048);
    dma16(ga + k0 + (size_t)64 * DIMC, la + 4096);
    dma16(ga + k0 + (size_t)96 * DIMC, la + 6144);
    dma16(gb + k0,                     lb);
    dma16(gb + k0 + (size_t)32 * DIMC, lb + 2048);
    dma16(gb + k0 + (size_t)64 * DIMC, lb + 4096);
    dma16(gb + k0 + (size_t)96 * DIMC, lb + 6144);
    __syncthreads();

#pragma unroll
    for (int kk = 0; kk < 2; ++kk) {
      const int cx = ((kk * 4 + g) ^ fx) * 8;
      bf16x8 af[4], bf[4];
#pragma unroll
      for (int i = 0; i < 4; ++i)
        af[i] = *(const bf16x8*)&lA[(wm + i * 16 + fr) * 64 + cx];
#pragma unroll
      for (int j = 0; j < 4; ++j)
        bf[j] = *(const bf16x8*)&lB[(wn + j * 16 + fr) * 64 + cx];
#pragma unroll
      for (int i = 0; i < 4; ++i)
#pragma unroll
        for (int j = 0; j < 4; ++j)
          acc[i][j] = __builtin_amdgcn_mfma_f32_16x16x32_bf16(af[i], bf[j], acc[i][j], 0, 0, 0);
    }
    __syncthreads();
  }

  const int col = lane & 15;
  const int rb = (lane >> 4) * 4;
  if (z < 2) {
    unsigned short* outp = z ? o1 : o0;
#pragma unroll
    for (int j = 0; j < 4; ++j) {
      const int gn = n0 + wn + j * 16 + col;
      const float bv = bias[gn];
#pragma unroll
      for (int i = 0; i < 4; ++i)
#pragma unroll
        for (int r = 0; r < 4; ++r) {
          const int gm = m0 + wm + i * 16 + rb + r;
          outp[(size_t)gm * DIMC + gn] = f2bf(acc[i][j][r] + bv);
        }
    }
  } else {
#pragma unroll
    for (int j = 0; j < 4; ++j) {
      const int gn = n0 + wn + j * 16 + col;      // d
      const float bv = bias[gn];
#pragma unroll
      for (int i = 0; i < 4; ++i) {
        const int base = wm + i * 16 + rb;
        const int tile = base & ~63;
        const int toka = m0 + tile + vperm4((base & 63) >> 2) * 4;
        uint2 pk;
        pk.x = (unsigned int)f2bf(acc[i][j][0] + bv) |
               ((unsigned int)f2bf(acc[i][j][1] + bv) << 16);
        pk.y = (unsigned int)f2bf(acc[i][j][2] + bv) |
               ((unsigned int)f2bf(acc[i][j][3] + bv) << 16);
        *(uint2*)(vt + (size_t)gn * LTOK + toka) = pk;
      }
    }
  }
}

// ---------------- wo GEMM: 64x128 tile (576 blocks), BK=64, single-buffer -----
__global__ __launch_bounds__(256)
void gemm_wo(const unsigned short* __restrict__ A,
             const unsigned short* __restrict__ Bw,
             const float* __restrict__ bias,
             float* __restrict__ outp)
{
  __shared__ __align__(16) unsigned short lA[64 * 64];
  __shared__ __align__(16) unsigned short lB[128 * 64];

  const int tid = threadIdx.x;
  const int wave = tid >> 6;
  const int lane = tid & 63;
  const int m0 = blockIdx.y * 64;
  const int n0 = blockIdx.x * 128;
  const int wm = (wave >> 1) * 32;
  const int wn = (wave & 1) * 64;

  f32x4 acc[2][4] = {};

  const int srow = tid >> 3;
  const int scol = ((tid & 7) ^ (srow & 7)) * 8;
  const unsigned short* ga = A  + (size_t)(m0 + srow) * DIMC + scol;
  const unsigned short* gb = Bw + (size_t)(n0 + srow) * DIMC + scol;
  unsigned short* la = lA + tid * 8;
  unsigned short* lb = lB + tid * 8;

  const int fr = lane & 15;
  const int g = lane >> 4;
  const int fx = fr & 7;

  for (int k0 = 0; k0 < DIMC; k0 += 64) {
    dma16(ga + k0,                     la);
    dma16(ga + k0 + (size_t)32 * DIMC, la + 2048);
    dma16(gb + k0,                     lb);
    dma16(gb + k0 + (size_t)32 * DIMC, lb + 2048);
    dma16(gb + k0 + (size_t)64 * DIMC, lb + 4096);
    dma16(gb + k0 + (size_t)96 * DIMC, lb + 6144);
    __syncthreads();

#pragma unroll
    for (int kk = 0; kk < 2; ++kk) {
      const int cx = ((kk * 4 + g) ^ fx) * 8;
      bf16x8 af[2], bf[4];
#pragma unroll
      for (int i = 0; i < 2; ++i)
        af[i] = *(const bf16x8*)&lA[(wm + i * 16 + fr) * 64 + cx];
#pragma unroll
      for (int j = 0; j < 4; ++j)
        bf[j] = *(const bf16x8*)&lB[(wn + j * 16 + fr) * 64 + cx];
#pragma unroll
      for (int i = 0; i < 2; ++i)
#pragma unroll
        for (int j = 0; j < 4; ++j)
          acc[i][j] = __builtin_amdgcn_mfma_f32_16x16x32_bf16(af[i], bf[j], acc[i][j], 0, 0, 0);
    }
    __syncthreads();
  }

  const int col = lane & 15;
  const int rb = (lane >> 4) * 4;
#pragma unroll
  for (int j = 0; j < 4; ++j) {
    const int gn = n0 + wn + j * 16 + col;
    const float bv = bias[gn];
#pragma unroll
    for (int i = 0; i < 2; ++i)
#pragma unroll
      for (int r = 0; r < 4; ++r) {
        const int gm = m0 + wm + i * 16 + rb + r;
        outp[(size_t)gm * DIMC + gn] = acc[i][j][r] + bv;
      }
  }
}

// ---------------- rmsnorm + 3D RoPE on q/k ------------------------------------
__global__ __launch_bounds__(256)
void post_qkv_k(unsigned short* __restrict__ q, unsigned short* __restrict__ k,
                const float* __restrict__ nqw, const float* __restrict__ nkw,
                const float* __restrict__ freqs)
{
  const int bx = blockIdx.x;
  const int tid = threadIdx.x;
  const int which = bx >= LTOK;
  const int tok = bx - which * LTOK;
  unsigned short* row = (which ? k : q) + (size_t)tok * DIMC;
  const float* nw = which ? nkw : nqw;
  const float sc = which ? 1.f : (0.08838834764831845f * 1.4426950408889634f);
  const int base = tid * 6;

  float vv[6];
  float ss = 0.f;
#pragma unroll
  for (int j = 0; j < 6; ++j) {
    vv[j] = bf2f(row[base + j]);
    ss += vv[j] * vv[j];
  }
#pragma unroll
  for (int off = 1; off < 64; off <<= 1) ss += __shfl_xor(ss, off);
  __shared__ float wsum[4];
  if ((tid & 63) == 0) wsum[tid >> 6] = ss;
  __syncthreads();
  const float total = wsum[0] + wsum[1] + wsum[2] + wsum[3];
  const float rms = rsqrtf(total * (1.f / DIMC) + 1e-6f);

  const int f = tok / FS;
  const int rem = tok - f * FS;
  const int h = rem / 24;
  const int w = rem - h * 24;

#pragma unroll
  for (int pp = 0; pp < 3; ++pp) {
    const int P = (base >> 1) + pp;
    const int p = P & 63;
    const int t = (p < 22) ? f : ((p < 43) ? h : w);
    const float fre = freqs[t * 128 + p * 2];
    const float fim = freqs[t * 128 + p * 2 + 1];
    const float e = vv[2 * pp]     * rms * nw[base + 2 * pp];
    const float o = vv[2 * pp + 1] * rms * nw[base + 2 * pp + 1];
    row[base + 2 * pp]     = f2bf((e * fre - o * fim) * sc);
    row[base + 2 * pp + 1] = f2bf((e * fim + o * fre) * sc);
  }
}

// ---------------- MFMA flash attention v5 -------------------------------------
// Single-buffered 32 KB LDS, 4 blocks/CU (launch_bounds(256,4)); grid 900:
//   bid<720:  heavy qb 9..23 (qf3-7), 4-way K-split, bf16 partials
//   <864:     mid   qb 3..8  (qf1-2), 2-way K-split, fp32 partials
//   <900:     light qb 0..2  (qf0),   direct output
// Latency hidden by 3.5 resident blocks/CU (R9 was grid-limited at 1.83).
__global__ __launch_bounds__(256, 4)
void attn_flash(const unsigned short* __restrict__ q,
                const unsigned short* __restrict__ k,
                const unsigned short* __restrict__ vt,
                unsigned short* __restrict__ ab,
                unsigned short* __restrict__ OpH, float* __restrict__ mlH,
                float* __restrict__ OpM, float* __restrict__ mlM)
{
  const int bid = blockIdx.x;
  int qb, head, chunk, nchunks;
  if (bid < 720)      { const int qh = bid >> 2; chunk = bid & 3; nchunks = 4; qb = 23 - qh / 12; head = qh % 12; }
  else if (bid < 864) { const int mb = bid - 720; const int qh = mb >> 1; chunk = mb & 1; nchunks = 2; qb = 8 - qh / 12; head = qh % 12; }
  else                { const int lb = bid - 864; qb = 2 - lb / 12; head = lb % 12; chunk = 0; nchunks = 1; }

  const int q0 = qb * 128;
  const int qf = qb / 3;
  const int kend = (qf + 1) * FS;
  const int s2 = kend - MAXATTN;
  const bool two = (s2 > FS);
  const int nt1 = (two ? FS : kend) >> 6;
  const int nt  = nt1 + (two ? (MAXATTN >> 6) : 0);
  const int tstart = chunk * nt / nchunks;
  const int tend = (chunk + 1) * nt / nchunks;

  const int tid = threadIdx.x;
  const int wave = tid >> 6, lane = tid & 63;
  const int col = lane & 15;
  const int g = lane >> 4;
  const int g4 = g * 4;

  __shared__ __align__(16) unsigned short Kl[64 * 128];   // XOR-swizzled chunks
  __shared__ __align__(16) unsigned short Vtl[128 * 64];

  bf16x8 qfA[4], qfB[4];
  {
    const unsigned short* qr0 = q + (size_t)(q0 + wave * 32 + col) * DIMC + head * HD;
#pragma unroll
    for (int kk = 0; kk < 4; ++kk) {
      qfA[kk] = *(const bf16x8*)(qr0 + kk * 32 + g * 8);
      qfB[kk] = *(const bf16x8*)(qr0 + (size_t)16 * DIMC + kk * 32 + g * 8);
    }
  }

  f32x4 o0[8] = {}, o1[8] = {};
  float m0 = -3.0e38f, l0 = 0.f, m1 = -3.0e38f, l1 = 0.f;

  const int krow = tid >> 4;
  const int kc8  = ((tid & 15) ^ krow) * 8;
  const unsigned short* kg = k + (size_t)krow * DIMC + head * HD + kc8;
  const int vrow = tid >> 3;
  const int vc8  = ((tid & 7) ^ (vrow & 7)) * 8;
  const unsigned short* vg = vt + ((size_t)head * HD + vrow) * LTOK + vc8;
  unsigned short* kl = Kl + tid * 8;
  unsigned short* vl = Vtl + tid * 8;

  for (int t = tstart; t < tend; ++t) {
    const int kb = (t < nt1) ? t * 64 : s2 + (t - nt1) * 64;
    const unsigned short* kp = kg + (size_t)kb * DIMC;
    dma16(kp,                     kl);
    dma16(kp + (size_t)16 * DIMC, kl + 16 * 128);
    dma16(kp + (size_t)32 * DIMC, kl + 32 * 128);
    dma16(kp + (size_t)48 * DIMC, kl + 48 * 128);
    const unsigned short* vp = vg + kb;
    dma16(vp,                     vl);
    dma16(vp + (size_t)32 * LTOK, vl + 32 * 64);
    dma16(vp + (size_t)64 * LTOK, vl + 64 * 64);
    dma16(vp + (size_t)96 * LTOK, vl + 96 * 64);
    __syncthreads();   // dma drained (vmcnt(0) before barrier)

    f32x4 sA[4] = {}, sB[4] = {};
#pragma unroll
    for (int kt = 0; kt < 4; ++kt) {
      const unsigned short* kr = &Kl[(kt * 16 + col) * 128];
#pragma unroll
      for (int kk = 0; kk < 4; ++kk) {
        bf16x8 kfr = *(const bf16x8*)(kr + ((kk * 4 + g) ^ col) * 8);
        sA[kt] = __builtin_amdgcn_mfma_f32_16x16x32_bf16(kfr, qfA[kk], sA[kt], 0, 0, 0);
        sB[kt] = __builtin_amdgcn_mfma_f32_16x16x32_bf16(kfr, qfB[kk], sB[kt], 0, 0, 0);
      }
    }

    unsigned int A0, A1, A2, A3, A4, A5, A6, A7;
    float alA;
    {
      float mx = sA[0][0];
#pragma unroll
      for (int kt = 0; kt < 4; ++kt)
#pragma unroll
        for (int r = 0; r < 4; ++r) mx = fmaxf(mx, sA[kt][r]);
      mx = fmaxf(mx, __shfl_xor(mx, 16));
      mx = fmaxf(mx, __shfl_xor(mx, 32));
      const float mn = fmaxf(m0, mx);
      alA = exp2f(m0 - mn);
      m0 = mn;
      float rs = 0.f;
#define PKA(KT, PA, PB)                                        \
      {                                                        \
        const unsigned short p0 = f2bf(exp2f(sA[KT][0] - mn)); \
        const unsigned short p1 = f2bf(exp2f(sA[KT][1] - mn)); \
        const unsigned short p2 = f2bf(exp2f(sA[KT][2] - mn)); \
        const unsigned short p3 = f2bf(exp2f(sA[KT][3] - mn)); \
        rs += bf2f(p0) + bf2f(p1) + bf2f(p2) + bf2f(p3);       \
        PA = (unsigned int)p0 | ((unsigned int)p1 << 16);      \
        PB = (unsigned int)p2 | ((unsigned int)p3 << 16);      \
      }
      PKA(0, A0, A1) PKA(1, A2, A3) PKA(2, A4, A5) PKA(3, A6, A7)
#undef PKA
      rs += __shfl_xor(rs, 16);
      rs += __shfl_xor(rs, 32);
      l0 = l0 * alA + rs;
    }
    unsigned int B0, B1, B2, B3, B4, B5, B6, B7;
    float alB;
    {
      float mx = sB[0][0];
#pragma unroll
      for (int kt = 0; kt < 4; ++kt)
#pragma unroll
        for (int r = 0; r < 4; ++r) mx = fmaxf(mx, sB[kt][r]);
      mx = fmaxf(mx, __shfl_xor(mx, 16));
      mx = fmaxf(mx, __shfl_xor(mx, 32));
      const float mn = fmaxf(m1, mx);
      alB = exp2f(m1 - mn);
      m1 = mn;
      float rs = 0.f;
#define PKB(KT, PA, PB)                                        \
      {                                                        \
        const unsigned short p0 = f2bf(exp2f(sB[KT][0] - mn)); \
        const unsigned short p1 = f2bf(exp2f(sB[KT][1] - mn)); \
        const unsigned short p2 = f2bf(exp2f(sB[KT][2] - mn)); \
        const unsigned short p3 = f2bf(exp2f(sB[KT][3] - mn)); \
        rs += bf2f(p0) + bf2f(p1) + bf2f(p2) + bf2f(p3);       \
        PA = (unsigned int)p0 | ((unsigned int)p1 << 16);      \
        PB = (unsigned int)p2 | ((unsigned int)p3 << 16);      \
      }
      PKB(0, B0, B1) PKB(1, B2, B3) PKB(2, B4, B5) PKB(3, B6, B7)
#undef PKB
      rs += __shfl_xor(rs, 16);
      rs += __shfl_xor(rs, 32);
      l1 = l1 * alB + rs;
    }

#pragma unroll
    for (int dt = 0; dt < 8; ++dt) { o0[dt] *= alA; o1[dt] *= alB; }

    u32x4 tA0, tA1, tB0, tB1;
    tA0[0] = A0; tA0[1] = A1; tA0[2] = A2; tA0[3] = A3;
    tA1[0] = A4; tA1[1] = A5; tA1[2] = A6; tA1[3] = A7;
    tB0[0] = B0; tB0[1] = B1; tB0[2] = B2; tB0[3] = B3;
    tB1[0] = B4; tB1[1] = B5; tB1[2] = B6; tB1[3] = B7;
    const bf16x8 pfA0 = __builtin_bit_cast(bf16x8, tA0);
    const bf16x8 pfA1 = __builtin_bit_cast(bf16x8, tA1);
    const bf16x8 pfB0 = __builtin_bit_cast(bf16x8, tB0);
    const bf16x8 pfB1 = __builtin_bit_cast(bf16x8, tB1);

    const int vx0 = (g ^ (col & 7)) * 8;
    const int vx1 = ((4 + g) ^ (col & 7)) * 8;
#pragma unroll
    for (int dt = 0; dt < 8; ++dt) {
      const unsigned short* vr = &Vtl[(dt * 16 + col) * 64];
      bf16x8 vf0 = *(const bf16x8*)(vr + vx0);
      o0[dt] = __builtin_amdgcn_mfma_f32_16x16x32_bf16(vf0, pfA0, o0[dt], 0, 0, 0);
      o1[dt] = __builtin_amdgcn_mfma_f32_16x16x32_bf16(vf0, pfB0, o1[dt], 0, 0, 0);
      bf16x8 vf1 = *(const bf16x8*)(vr + vx1);
      o0[dt] = __builtin_amdgcn_mfma_f32_16x16x32_bf16(vf1, pfA1, o0[dt], 0, 0, 0);
      o1[dt] = __builtin_amdgcn_mfma_f32_16x16x32_bf16(vf1, pfB1, o1[dt], 0, 0, 0);
    }
    __syncthreads();   // reads done before next tile's dma overwrites
  }

  const int qrow0 = q0 + wave * 32 + col;
  if (nchunks == 1) {
    const float i0 = 1.f / l0, i1 = 1.f / l1;
    unsigned short* or0 = ab + (size_t)qrow0 * DIMC + head * HD;
    unsigned short* or1 = or0 + (size_t)16 * DIMC;
#pragma unroll
    for (int dt = 0; dt < 8; ++dt) {
      uint2 pk;
      pk.x = (unsigned int)f2bf(o0[dt][0] * i0) | ((unsigned int)f2bf(o0[dt][1] * i0) << 16);
      pk.y = (unsigned int)f2bf(o0[dt][2] * i0) | ((unsigned int)f2bf(o0[dt][3] * i0) << 16);
      *(uint2*)(or0 + dt * 16 + g4) = pk;
      pk.x = (unsigned int)f2bf(o1[dt][0] * i1) | ((unsigned int)f2bf(o1[dt][1] * i1) << 16);
      pk.y = (unsigned int)f2bf(o1[dt][2] * i1) | ((unsigned int)f2bf(o1[dt][3] * i1) << 16);
      *(uint2*)(or1 + dt * 16 + g4) = pk;
    }
  } else if (nchunks == 2) {          // mid: fp32 partials
    const int tokm0 = qrow0 - MTOK;
    float* ob0 = OpM + ((size_t)(chunk * NMT + tokm0) * HEADS + head) * HD;
    float* ob1 = OpM + ((size_t)(chunk * NMT + tokm0 + 16) * HEADS + head) * HD;
#pragma unroll
    for (int dt = 0; dt < 8; ++dt) {
      *(f32x4*)(ob0 + dt * 16 + g4) = o0[dt];
      *(f32x4*)(ob1 + dt * 16 + g4) = o1[dt];
    }
    if (lane < 16) {
      float* p0 = mlM + 2 * ((size_t)(chunk * NMT + tokm0) * HEADS + head);
      float* p1 = mlM + 2 * ((size_t)(chunk * NMT + tokm0 + 16) * HEADS + head);
      p0[0] = m0; p0[1] = l0;
      p1[0] = m1; p1[1] = l1;
    }
  } else {                            // heavy: bf16 partials
    const int tokp0 = qrow0 - HTOK;
    unsigned short* ob0 = OpH + ((size_t)(chunk * NHT + tokp0) * HEADS + head) * HD;
    unsigned short* ob1 = OpH + ((size_t)(chunk * NHT + tokp0 + 16) * HEADS + head) * HD;
#pragma unroll
    for (int dt = 0; dt < 8; ++dt) {
      uint2 pk;
      pk.x = (unsigned int)f2bf(o0[dt][0]) | ((unsigned int)f2bf(o0[dt][1]) << 16);
      pk.y = (unsigned int)f2bf(o0[dt][2]) | ((unsigned int)f2bf(o0[dt][3]) << 16);
      *(uint2*)(ob0 + dt * 16 + g4) = pk;
      pk.x = (unsigned int)f2bf(o1[dt][0]) | ((unsigned int)f2bf(o1[dt][1]) << 16);
      pk.y = (unsigned int)f2bf(o1[dt][2]) | ((unsigned int)f2bf(o1[dt][3]) << 16);
      *(uint2*)(ob1 + dt * 16 + g4) = pk;
    }
    if (lane < 16) {
      float* p0 = mlH + 2 * ((size_t)(chunk * NHT + tokp0) * HEADS + head);
      float* p1 = mlH + 2 * ((size_t)(chunk * NHT + tokp0 + 16) * HEADS + head);
      p0[0] = m0; p0[1] = l0;
      p1[0] = m1; p1[1] = l1;
    }
  }
}

// ---------------- merge 4 bf16 chunks (heavy tokens) ----------------
__global__ __launch_bounds__(384)
void merge_h(const unsigned short* __restrict__ OpH, const float* __restrict__ mlH,
             unsigned short* __restrict__ ab)
{
  const int tokp = blockIdx.x;           // 0..1919
  const int tid = threadIdx.x;           // 0..383
  const int e = tid * 4;
  const int head = e >> 7;
  const int d = e & 127;

  float mc0, mc1, mc2, mc3, lc0, lc1, lc2, lc3;
  {
    const float* p0 = mlH + 2 * ((size_t)(0 * NHT + tokp) * HEADS + head);
    const float* p1 = mlH + 2 * ((size_t)(1 * NHT + tokp) * HEADS + head);
    const float* p2 = mlH + 2 * ((size_t)(2 * NHT + tokp) * HEADS + head);
    const float* p3 = mlH + 2 * ((size_t)(3 * NHT + tokp) * HEADS + head);
    mc0 = p0[0]; lc0 = p0[1]; mc1 = p1[0]; lc1 = p1[1];
    mc2 = p2[0]; lc2 = p2[1]; mc3 = p3[0]; lc3 = p3[1];
  }
  const float mm = fmaxf(fmaxf(mc0, mc1), fmaxf(mc2, mc3));
  const float a0 = exp2f(mc0 - mm), a1 = exp2f(mc1 - mm);
  const float a2 = exp2f(mc2 - mm), a3 = exp2f(mc3 - mm);
  const float inv = 1.f / (lc0 * a0 + lc1 * a1 + lc2 * a2 + lc3 * a3);

  float acc0 = 0.f, acc1 = 0.f, acc2 = 0.f, acc3 = 0.f;
#define ACCC(C, AC)                                                        \
  {                                                                        \
    uint2 v = *(const uint2*)(OpH + ((size_t)(C * NHT + tokp) * HEADS + head) * HD + d); \
    acc0 += AC * bf2f((unsigned short)(v.x & 0xffff));                     \
    acc1 += AC * bf2f((unsigned short)(v.x >> 16));                        \
    acc2 += AC * bf2f((unsigned short)(v.y & 0xffff));                     \
    acc3 += AC * bf2f((unsigned short)(v.y >> 16));                        \
  }
  ACCC(0, a0) ACCC(1, a1) ACCC(2, a2) ACCC(3, a3)
#undef ACCC
  uint2 pk;
  pk.x = (unsigned int)f2bf(acc0 * inv) | ((unsigned int)f2bf(acc1 * inv) << 16);
  pk.y = (unsigned int)f2bf(acc2 * inv) | ((unsigned int)f2bf(acc3 * inv) << 16);
  *(uint2*)(ab + (size_t)(HTOK + tokp) * DIMC + e) = pk;
}

// ---------------- merge 2 fp32 chunks (mid tokens) ----------------
__global__ __launch_bounds__(384)
void merge_m(const float* __restrict__ OpM, const float* __restrict__ mlM,
             unsigned short* __restrict__ ab)
{
  const int tokm = blockIdx.x;           // 0..767
  const int tid = threadIdx.x;
  const int e = tid * 4;
  const int head = e >> 7;
  const int d = e & 127;
  const size_t r0 = ((size_t)(0 * NMT + tokm) * HEADS + head) * HD + d;
  const size_t r1 = ((size_t)(1 * NMT + tokm) * HEADS + head) * HD + d;
  float4 o0 = *(const float4*)(OpM + r0);
  float4 o1 = *(const float4*)(OpM + r1);
  const float* ml0 = mlM + 2 * ((size_t)(0 * NMT + tokm) * HEADS + head);
  const float* ml1 = mlM + 2 * ((size_t)(1 * NMT + tokm) * HEADS + head);
  const float m0 = ml0[0], l0 = ml0[1], m1 = ml1[0], l1 = ml1[1];
  const float mm = fmaxf(m0, m1);
  const float a0 = exp2f(m0 - mm), a1 = exp2f(m1 - mm);
  const float inv = 1.f / (l0 * a0 + l1 * a1);
  uint2 pk;
  pk.x = (unsigned int)f2bf((o0.x * a0 + o1.x * a1) * inv) |
         ((unsigned int)f2bf((o0.y * a0 + o1.y * a1) * inv) << 16);
  pk.y = (unsigned int)f2bf((o0.z * a0 + o1.z * a1) * inv) |
         ((unsigned int)f2bf((o0.w * a0 + o1.w * a1) * inv) << 16);
  *(uint2*)(ab + (size_t)(MTOK + tokm) * DIMC + e) = pk;
}

// ---------------- launch ----------------
extern "C" void kernel_launch(void* const* d_in, const int* in_sizes, int n_in,
                              void* d_out, int out_size, void* d_ws, size_t ws_size,
                              hipStream_t stream)
{
  (void)in_sizes; (void)n_in; (void)out_size; (void)ws_size;
  const float* x     = (const float*)d_in[0];
  const float* freqs = (const float*)d_in[3];
  const float* wq    = (const float*)d_in[4];
  const float* bq    = (const float*)d_in[5];
  const float* wk    = (const float*)d_in[6];
  const float* bk    = (const float*)d_in[7];
  const float* wv    = (const float*)d_in[8];
  const float* bv    = (const float*)d_in[9];
  const float* wo    = (const float*)d_in[10];
  const float* bo    = (const float*)d_in[11];
  const float* nqw   = (const float*)d_in[12];
  const float* nkw   = (const float*)d_in[13];

  char* ws = (char*)d_ws;
  size_t off = 0;
  auto take = [&](size_t bytes) -> void* {
    void* p = ws + off; off += (bytes + 255) & ~(size_t)255; return p;
  };
  // Overlays: OpH (bf16, 4 chunks x 1920 tok) = xb+wqb+wkb+wvb (23.6 MB, dead
  // after QKV GEMM); OpM (fp32, 2 chunks x 768 tok) = vb (9.44 MB, unused).
  unsigned short* wob = (unsigned short*)take((size_t)DIMC * DIMC * 2);
  unsigned short* qb  = (unsigned short*)take((size_t)LTOK * DIMC * 2);
  unsigned short* kb  = (unsigned short*)take((size_t)LTOK * DIMC * 2);
  unsigned short* vb  = (unsigned short*)take((size_t)LTOK * DIMC * 2);
  unsigned short* ab  = (unsigned short*)take((size_t)LTOK * DIMC * 2);
  unsigned short* vtb = (unsigned short*)take((size_t)LTOK * DIMC * 2);
  unsigned short* xb  = (unsigned short*)take((size_t)LTOK * DIMC * 2);
  unsigned short* wqb = (unsigned short*)take((size_t)DIMC * DIMC * 2);
  unsigned short* wkb = (unsigned short*)take((size_t)DIMC * DIMC * 2);
  unsigned short* wvb = (unsigned short*)take((size_t)DIMC * DIMC * 2);
  float* mlH = (float*)take((size_t)4 * NHT * HEADS * 2 * sizeof(float));
  float* mlM = (float*)take((size_t)2 * NMT * HEADS * 2 * sizeof(float));
  unsigned short* OpH = xb;      // 4*1920*12*128*2 B = 23.59 MB
  float* OpM = (float*)vb;       // 2*768*12*128*4 B  = 9.44 MB

  cvt_all_k<<<dim3(13824), dim3(256), 0, stream>>>(x, wq, wk, wv, wo,
                                                   xb, wqb, wkb, wvb, wob);

  gemm_qkv<<<dim3(DIMC / 128, LTOK / 128, 3), dim3(256), 0, stream>>>(
      xb, wqb, wkb, wvb, bq, bk, bv, qb, kb, vtb);

  post_qkv_k<<<dim3(2 * LTOK), dim3(256), 0, stream>>>(qb, kb, nqw, nkw, freqs);

  attn_flash<<<dim3(900), dim3(256), 0, stream>>>(qb, kb, vtb, ab,
                                                  OpH, mlH, OpM, mlM);
  merge_h<<<dim3(NHT), dim3(384), 0, stream>>>(OpH, mlH, ab);
  merge_m<<<dim3(NMT), dim3(384), 0, stream>>>(OpM, mlM, ab);

  gemm_wo<<<dim3(DIMC / 128, LTOK / 64), dim3(256), 0, stream>>>(
      ab, wob, bo, (float*)d_out);
}